// Round 2
// baseline (1407.155 us; speedup 1.0000x reference)
//
#include <hip/hip_runtime.h>

#define N_NODES 100000
#define N_EDGES 1600000
#define N_GRAPHS 512
#define BN_EPS 1e-5f

typedef __bf16 bf16x8 __attribute__((ext_vector_type(8)));
typedef __bf16 bf16x4 __attribute__((ext_vector_type(4)));
typedef float  f32x4  __attribute__((ext_vector_type(4)));

// ---------------- small prep kernels ----------------

__global__ void conv_x_kernel(const float* __restrict__ x, __bf16* __restrict__ xb) {
    int i = blockIdx.x * 256 + threadIdx.x;            // one per 4 elems
    if (i < (N_NODES * 128) / 4) {
        float4 v = ((const float4*)x)[i];
        bf16x4 o;
        o[0] = (__bf16)v.x; o[1] = (__bf16)v.y; o[2] = (__bf16)v.z; o[3] = (__bf16)v.w;
        ((bf16x4*)xb)[i] = o;
    }
}

// w1:[4][128][256] -> w1T:[4][256][128]; w2:[4][256][128] -> w2T:[4][128][256]
__global__ void conv_w_kernel(const float* __restrict__ w1, const float* __restrict__ w2,
                              __bf16* __restrict__ w1T, __bf16* __restrict__ w2T) {
    int i = blockIdx.x * 256 + threadIdx.x;
    if (i < 4 * 128 * 256) {
        int l = i >> 15, r = i & 32767;
        int k = r >> 8, n = r & 255;
        w1T[(l << 15) + n * 128 + k] = (__bf16)w1[i];
        int k2 = r >> 7, n2 = r & 127;
        w2T[(l << 15) + n2 * 256 + k2] = (__bf16)w2[i];
    }
}

__global__ void count_deg_kernel(const int* __restrict__ dstv, int* __restrict__ deg) {
    int i = blockIdx.x * 256 + threadIdx.x;
    if (i < N_EDGES) atomicAdd(&deg[dstv[i]], 1);
}

__global__ void scan_blocks_kernel(const int* __restrict__ deg, int* __restrict__ partial,
                                   int* __restrict__ bsums, int n) {
    __shared__ int s[256];
    int t = threadIdx.x;
    int i = blockIdx.x * 256 + t;
    int v = (i < n) ? deg[i] : 0;
    s[t] = v; __syncthreads();
    for (int off = 1; off < 256; off <<= 1) {
        int x = (t >= off) ? s[t - off] : 0;
        __syncthreads();
        s[t] += x;
        __syncthreads();
    }
    if (i < n) partial[i] = s[t];
    if (t == 255) bsums[blockIdx.x] = s[255];
}

__global__ void scan_bsums_kernel(int* __restrict__ bsums, int nb) {
    __shared__ int s[512];
    int t = threadIdx.x;
    s[t] = (t < nb) ? bsums[t] : 0; __syncthreads();
    for (int off = 1; off < 512; off <<= 1) {
        int x = (t >= off) ? s[t - off] : 0;
        __syncthreads();
        s[t] += x;
        __syncthreads();
    }
    if (t < nb) bsums[t] = s[t];   // inclusive
}

__global__ void add_offsets_kernel(const int* __restrict__ partial, const int* __restrict__ bsums,
                                   int* __restrict__ rowptr, int n) {
    int i = blockIdx.x * 256 + threadIdx.x;
    int add = (blockIdx.x > 0) ? bsums[blockIdx.x - 1] : 0;
    if (i < n) rowptr[i + 1] = partial[i] + add;
    if (i == 0) rowptr[0] = 0;
}

__global__ void init_cursor_kernel(const int* __restrict__ rowptr, int* __restrict__ cursor) {
    int i = blockIdx.x * 256 + threadIdx.x;
    if (i < N_NODES) cursor[i] = rowptr[i];
}

__global__ void fill_eidx_kernel(const int* __restrict__ srcv, const int* __restrict__ dstv,
                                 int* __restrict__ cursor, int* __restrict__ eidx) {
    int i = blockIdx.x * 256 + threadIdx.x;
    if (i < N_EDGES) {
        int p = atomicAdd(&cursor[dstv[i]], 1);
        eidx[p] = srcv[i];
    }
}

// ---------------- fused GIN layer GEMMs ----------------
// GEMM1: A = (1+eps)*x + sum_neighbors(x)  [M x 128] (staged with fused CSR gather)
//        B = w1T[l]  [256][128]  -> h1 = relu(bn1(A@w1 + b1))  bf16 [M x 256]

__global__ __launch_bounds__(256) void gin_gemm1(
    const __bf16* __restrict__ xb, const int* __restrict__ rowptr, const int* __restrict__ eidx,
    const __bf16* __restrict__ w1T, const float* __restrict__ b1,
    const float* __restrict__ g1, const float* __restrict__ bb1,
    const float* __restrict__ m1, const float* __restrict__ v1,
    const float* __restrict__ gin_eps, int layer, __bf16* __restrict__ h1)
{
    __shared__ __align__(16) __bf16 As[64 * 136];   // K=128 pad 8
    __shared__ __align__(16) __bf16 Bs[256 * 136];  // n-major
    int tid = threadIdx.x;
    int bm = blockIdx.x * 64;
    float eps1 = 1.0f + gin_eps[layer];

    // ---- stage A with fused aggregation: 4 threads per row, 32 ch each ----
    {
        int r = tid >> 2;
        int c0 = (tid & 3) * 32;
        int row = bm + r;
        float acc[32];
        #pragma unroll
        for (int j = 0; j < 32; j++) acc[j] = 0.0f;
        if (row < N_NODES) {
            const __bf16* xr = xb + (size_t)row * 128 + c0;
            bf16x8 s0 = *(const bf16x8*)(xr);
            bf16x8 s1 = *(const bf16x8*)(xr + 8);
            bf16x8 s2 = *(const bf16x8*)(xr + 16);
            bf16x8 s3 = *(const bf16x8*)(xr + 24);
            #pragma unroll
            for (int j = 0; j < 8; j++) {
                acc[j]      = eps1 * (float)s0[j];
                acc[8 + j]  = eps1 * (float)s1[j];
                acc[16 + j] = eps1 * (float)s2[j];
                acc[24 + j] = eps1 * (float)s3[j];
            }
            int e0 = rowptr[row], e1 = rowptr[row + 1];
            for (int e = e0; e < e1; ++e) {
                const __bf16* sr = xb + (size_t)eidx[e] * 128 + c0;
                bf16x8 u0 = *(const bf16x8*)(sr);
                bf16x8 u1 = *(const bf16x8*)(sr + 8);
                bf16x8 u2 = *(const bf16x8*)(sr + 16);
                bf16x8 u3 = *(const bf16x8*)(sr + 24);
                #pragma unroll
                for (int j = 0; j < 8; j++) {
                    acc[j]      += (float)u0[j];
                    acc[8 + j]  += (float)u1[j];
                    acc[16 + j] += (float)u2[j];
                    acc[24 + j] += (float)u3[j];
                }
            }
        }
        __bf16* arow = &As[r * 136 + c0];
        #pragma unroll
        for (int q = 0; q < 4; q++) {
            bf16x8 t;
            #pragma unroll
            for (int j = 0; j < 8; j++) t[j] = (__bf16)acc[q * 8 + j];
            *(bf16x8*)(arow + q * 8) = t;
        }
    }
    // ---- stage B: copy w1T (256x128 bf16) ----
    for (int i = tid; i < 4096; i += 256) {       // 4096 chunks of 8
        int n = i >> 4;
        int kc = (i & 15) * 8;
        *(bf16x8*)&Bs[n * 136 + kc] = *(const bf16x8*)&w1T[n * 128 + kc];
    }
    __syncthreads();

    // ---- MFMA: wave wv handles rows [wv*16, wv*16+16), loops 16 n-tiles ----
    int wv = tid >> 6, lane = tid & 63;
    int am = wv * 16 + (lane & 15);
    int ak0 = (lane >> 4) * 8;
    bf16x8 af[4];
    #pragma unroll
    for (int ks = 0; ks < 4; ks++) af[ks] = *(const bf16x8*)&As[am * 136 + ks * 32 + ak0];
    int cn = lane & 15;
    int rq = (lane >> 4) * 4;
    for (int nt = 0; nt < 16; nt++) {
        f32x4 acc = {0.f, 0.f, 0.f, 0.f};
        int n = nt * 16 + cn;
        #pragma unroll
        for (int ks = 0; ks < 4; ks++) {
            bf16x8 bf = *(const bf16x8*)&Bs[n * 136 + ks * 32 + ak0];
            acc = __builtin_amdgcn_mfma_f32_16x16x32_bf16(af[ks], bf, acc, 0, 0, 0);
        }
        float s = g1[n] * rsqrtf(v1[n] + BN_EPS);
        float c = (b1[n] - m1[n]) * s + bb1[n];
        #pragma unroll
        for (int r2 = 0; r2 < 4; r2++) {
            int row = bm + wv * 16 + rq + r2;
            if (row < N_NODES) {
                float z = acc[r2] * s + c;
                h1[(size_t)row * 256 + n] = (__bf16)fmaxf(z, 0.0f);
            }
        }
    }
}

// GEMM2: x_out = relu(bn2(h1 @ w2 + b2))  [M x 128], K=256
__global__ __launch_bounds__(256) void gin_gemm2(
    const __bf16* __restrict__ h1, const __bf16* __restrict__ w2T,
    const float* __restrict__ b2, const float* __restrict__ g2, const float* __restrict__ bb2,
    const float* __restrict__ m2, const float* __restrict__ v2, __bf16* __restrict__ xout)
{
    __shared__ __align__(16) __bf16 As[64 * 264];   // K=256 pad 8
    __shared__ __align__(16) __bf16 Bs[128 * 264];
    int tid = threadIdx.x;
    int bm = blockIdx.x * 64;

    for (int i = tid; i < 2048; i += 256) {        // A: 64x256 = 2048 chunks of 8
        int r = i >> 5;
        int kc = (i & 31) * 8;
        int row = bm + r;
        bf16x8 val;
        #pragma unroll
        for (int j = 0; j < 8; j++) val[j] = (__bf16)0.0f;
        if (row < N_NODES) val = *(const bf16x8*)&h1[(size_t)row * 256 + kc];
        *(bf16x8*)&As[r * 264 + kc] = val;
    }
    for (int i = tid; i < 4096; i += 256) {        // B: 128x256
        int n = i >> 5;
        int kc = (i & 31) * 8;
        *(bf16x8*)&Bs[n * 264 + kc] = *(const bf16x8*)&w2T[n * 256 + kc];
    }
    __syncthreads();

    int wv = tid >> 6, lane = tid & 63;
    int am = wv * 16 + (lane & 15);
    int ak0 = (lane >> 4) * 8;
    bf16x8 af[8];
    #pragma unroll
    for (int ks = 0; ks < 8; ks++) af[ks] = *(const bf16x8*)&As[am * 264 + ks * 32 + ak0];
    int cn = lane & 15;
    int rq = (lane >> 4) * 4;
    for (int nt = 0; nt < 8; nt++) {
        f32x4 acc = {0.f, 0.f, 0.f, 0.f};
        int n = nt * 16 + cn;
        #pragma unroll
        for (int ks = 0; ks < 8; ks++) {
            bf16x8 bf = *(const bf16x8*)&Bs[n * 264 + ks * 32 + ak0];
            acc = __builtin_amdgcn_mfma_f32_16x16x32_bf16(af[ks], bf, acc, 0, 0, 0);
        }
        float s = g2[n] * rsqrtf(v2[n] + BN_EPS);
        float c = (b2[n] - m2[n]) * s + bb2[n];
        #pragma unroll
        for (int r2 = 0; r2 < 4; r2++) {
            int row = bm + wv * 16 + rq + r2;
            if (row < N_NODES) {
                float z = acc[r2] * s + c;
                xout[(size_t)row * 128 + n] = (__bf16)fmaxf(z, 0.0f);
            }
        }
    }
}

// ---------------- pooling + head ----------------

__global__ void pool_kernel(const __bf16* __restrict__ xb, const int* __restrict__ batch,
                            float* __restrict__ pooled) {
    int i = blockIdx.x * 256 + threadIdx.x;
    if (i < N_NODES * 128) {
        int node = i >> 7;
        int c = i & 127;
        unsafeAtomicAdd(&pooled[batch[node] * 128 + c], (float)xb[i]);
    }
}

__global__ void final_kernel(const float* __restrict__ pooled,
                             const float* __restrict__ lw1, const float* __restrict__ lb1,
                             const float* __restrict__ g3, const float* __restrict__ b3,
                             const float* __restrict__ m3, const float* __restrict__ v3,
                             const float* __restrict__ lw2, const float* __restrict__ lb2,
                             float* __restrict__ out) {
    int gid = blockIdx.x;
    int t = threadIdx.x;
    __shared__ float p[128], hs[128], lg[10];
    p[t] = pooled[gid * 128 + t];
    __syncthreads();
    float z = lb1[t];
    #pragma unroll 4
    for (int k = 0; k < 128; k++) z += p[k] * lw1[k * 128 + t];
    float h = (z - m3[t]) * rsqrtf(v3[t] + BN_EPS) * g3[t] + b3[t];
    hs[t] = fmaxf(h, 0.0f);
    __syncthreads();
    if (t < 10) {
        float o = lb2[t];
        #pragma unroll 4
        for (int k = 0; k < 128; k++) o += hs[k] * lw2[k * 10 + t];
        lg[t] = o;
    }
    __syncthreads();
    if (t < 10) {
        float mx = lg[0];
        for (int j = 1; j < 10; j++) mx = fmaxf(mx, lg[j]);
        float sum = 0.0f;
        for (int j = 0; j < 10; j++) sum += expf(lg[j] - mx);
        out[gid * 10 + t] = lg[t] - mx - logf(sum);
    }
}

// ---------------- launch ----------------

extern "C" void kernel_launch(void* const* d_in, const int* in_sizes, int n_in,
                              void* d_out, int out_size, void* d_ws, size_t ws_size,
                              hipStream_t stream) {
    (void)in_sizes; (void)n_in; (void)out_size; (void)ws_size;
    const float* x      = (const float*)d_in[0];
    const int*   ei     = (const int*)d_in[1];
    const int*   srcv   = ei;
    const int*   dstv   = ei + N_EDGES;
    const int*   batch  = (const int*)d_in[2];
    const float* w1     = (const float*)d_in[3];
    const float* b1     = (const float*)d_in[4];
    const float* bn1_g  = (const float*)d_in[5];
    const float* bn1_b  = (const float*)d_in[6];
    const float* bn1_m  = (const float*)d_in[7];
    const float* bn1_v  = (const float*)d_in[8];
    const float* geps   = (const float*)d_in[9];
    const float* w2     = (const float*)d_in[10];
    const float* b2     = (const float*)d_in[11];
    const float* bn2_g  = (const float*)d_in[12];
    const float* bn2_b  = (const float*)d_in[13];
    const float* bn2_m  = (const float*)d_in[14];
    const float* bn2_v  = (const float*)d_in[15];
    const float* lw1    = (const float*)d_in[16];
    const float* lb1    = (const float*)d_in[17];
    const float* g3     = (const float*)d_in[18];
    const float* b3     = (const float*)d_in[19];
    const float* m3     = (const float*)d_in[20];
    const float* v3     = (const float*)d_in[21];
    const float* lw2    = (const float*)d_in[22];
    const float* lb2    = (const float*)d_in[23];
    float* out = (float*)d_out;

    char* ws = (char*)d_ws;
    __bf16* xb    = (__bf16*)(ws + 0);
    __bf16* h1    = (__bf16*)(ws + 25600000);
    __bf16* w1T   = (__bf16*)(ws + 76800000);
    __bf16* w2T   = (__bf16*)(ws + 77062144);
    int*    deg   = (int*)   (ws + 77324288);
    int*    part  = (int*)   (ws + 77724416);
    int*    rowp  = (int*)   (ws + 78124544);
    int*    curs  = (int*)   (ws + 78524672);
    int*    eidx  = (int*)   (ws + 78924800);
    int*    bsum  = (int*)   (ws + 85324800);
    float*  pooled= (float*) (ws + 85326848);

    (void)hipMemsetAsync(deg, 0, N_NODES * sizeof(int), stream);
    (void)hipMemsetAsync(pooled, 0, N_GRAPHS * 128 * sizeof(float), stream);

    conv_x_kernel<<<(N_NODES * 128 / 4 + 255) / 256, 256, 0, stream>>>(x, xb);
    conv_w_kernel<<<(4 * 128 * 256 + 255) / 256, 256, 0, stream>>>(w1, w2, w1T, w2T);
    count_deg_kernel<<<(N_EDGES + 255) / 256, 256, 0, stream>>>(dstv, deg);

    int nb = (N_NODES + 255) / 256;  // 391
    scan_blocks_kernel<<<nb, 256, 0, stream>>>(deg, part, bsum, N_NODES);
    scan_bsums_kernel<<<1, 512, 0, stream>>>(bsum, nb);
    add_offsets_kernel<<<nb, 256, 0, stream>>>(part, bsum, rowp, N_NODES);
    init_cursor_kernel<<<(N_NODES + 255) / 256, 256, 0, stream>>>(rowp, curs);
    fill_eidx_kernel<<<(N_EDGES + 255) / 256, 256, 0, stream>>>(srcv, dstv, curs, eidx);

    int mblocks = (N_NODES + 63) / 64;  // 1563
    for (int l = 0; l < 4; l++) {
        gin_gemm1<<<mblocks, 256, 0, stream>>>(
            xb, rowp, eidx, w1T + l * 32768,
            b1 + l * 256, bn1_g + l * 256, bn1_b + l * 256, bn1_m + l * 256, bn1_v + l * 256,
            geps, l, h1);
        gin_gemm2<<<mblocks, 256, 0, stream>>>(
            h1, w2T + l * 32768,
            b2 + l * 128, bn2_g + l * 128, bn2_b + l * 128, bn2_m + l * 128, bn2_v + l * 128,
            xb);
    }

    pool_kernel<<<(N_NODES * 128 + 255) / 256, 256, 0, stream>>>(xb, batch, pooled);
    final_kernel<<<N_GRAPHS, 128, 0, stream>>>(pooled, lw1, lb1, g3, b3, m3, v3, lw2, lb2, out);
}

// Round 3
// 877.570 us; speedup vs baseline: 1.6035x; 1.6035x over previous
//
#include <hip/hip_runtime.h>

#define N_NODES 100000
#define N_EDGES 1600000
#define N_GRAPHS 512
#define BN_EPS 1e-5f

typedef __bf16 bf16x8 __attribute__((ext_vector_type(8)));
typedef __bf16 bf16x4 __attribute__((ext_vector_type(4)));
typedef float  f32x4  __attribute__((ext_vector_type(4)));

// ---------------- small prep kernels ----------------

__global__ void conv_x_kernel(const float* __restrict__ x, __bf16* __restrict__ xb) {
    int i = blockIdx.x * 256 + threadIdx.x;            // one per 4 elems
    if (i < (N_NODES * 128) / 4) {
        float4 v = ((const float4*)x)[i];
        bf16x4 o;
        o[0] = (__bf16)v.x; o[1] = (__bf16)v.y; o[2] = (__bf16)v.z; o[3] = (__bf16)v.w;
        ((bf16x4*)xb)[i] = o;
    }
}

// Swizzled fragment-order weights:
// w1:[4][128][256] -> w1S: elem = l*32768 + (k>>3)*2048 + n*8 + (k&7)
// w2:[4][256][128] -> w2S: elem = l*32768 + (k>>3)*1024 + n*8 + (k&7)
__global__ void conv_w_kernel(const float* __restrict__ w1, const float* __restrict__ w2,
                              __bf16* __restrict__ w1S, __bf16* __restrict__ w2S) {
    int i = blockIdx.x * 256 + threadIdx.x;
    if (i < 4 * 128 * 256) {
        int l = i >> 15, r = i & 32767;
        int k = r >> 8, n = r & 255;
        w1S[(l << 15) + (k >> 3) * 2048 + n * 8 + (k & 7)] = (__bf16)w1[i];
        int k2 = r >> 7, n2 = r & 127;
        w2S[(l << 15) + (k2 >> 3) * 1024 + n2 * 8 + (k2 & 7)] = (__bf16)w2[i];
    }
}

__global__ void count_deg_kernel(const int* __restrict__ dstv, int* __restrict__ deg) {
    int i = blockIdx.x * 256 + threadIdx.x;
    if (i < N_EDGES) atomicAdd(&deg[dstv[i]], 1);
}

__global__ void scan_blocks_kernel(const int* __restrict__ deg, int* __restrict__ partial,
                                   int* __restrict__ bsums, int n) {
    __shared__ int s[256];
    int t = threadIdx.x;
    int i = blockIdx.x * 256 + t;
    int v = (i < n) ? deg[i] : 0;
    s[t] = v; __syncthreads();
    for (int off = 1; off < 256; off <<= 1) {
        int x = (t >= off) ? s[t - off] : 0;
        __syncthreads();
        s[t] += x;
        __syncthreads();
    }
    if (i < n) partial[i] = s[t];
    if (t == 255) bsums[blockIdx.x] = s[255];
}

__global__ void scan_bsums_kernel(int* __restrict__ bsums, int nb) {
    __shared__ int s[512];
    int t = threadIdx.x;
    s[t] = (t < nb) ? bsums[t] : 0; __syncthreads();
    for (int off = 1; off < 512; off <<= 1) {
        int x = (t >= off) ? s[t - off] : 0;
        __syncthreads();
        s[t] += x;
        __syncthreads();
    }
    if (t < nb) bsums[t] = s[t];   // inclusive
}

__global__ void add_offsets_kernel(const int* __restrict__ partial, const int* __restrict__ bsums,
                                   int* __restrict__ rowptr, int n) {
    int i = blockIdx.x * 256 + threadIdx.x;
    int add = (blockIdx.x > 0) ? bsums[blockIdx.x - 1] : 0;
    if (i < n) rowptr[i + 1] = partial[i] + add;
    if (i == 0) rowptr[0] = 0;
}

__global__ void init_cursor_kernel(const int* __restrict__ rowptr, int* __restrict__ cursor) {
    int i = blockIdx.x * 256 + threadIdx.x;
    if (i < N_NODES) cursor[i] = rowptr[i];
}

__global__ void fill_eidx_kernel(const int* __restrict__ srcv, const int* __restrict__ dstv,
                                 int* __restrict__ cursor, int* __restrict__ eidx) {
    int i = blockIdx.x * 256 + threadIdx.x;
    if (i < N_EDGES) {
        int p = atomicAdd(&cursor[dstv[i]], 1);
        eidx[p] = srcv[i];
    }
}

// ---------------- fused GIN layer GEMMs (LDS-free) ----------------
// GEMM1: per-lane register gather of A = (1+eps)*x + sum_neighbors(x), then
// MFMA vs w1S read straight from global (L1/L2-resident, coalesced frag order).

__global__ __launch_bounds__(256) void gin_gemm1(
    const __bf16* __restrict__ xb, const int* __restrict__ rowptr, const int* __restrict__ eidx,
    const __bf16* __restrict__ w1S, const float* __restrict__ b1,
    const float* __restrict__ g1, const float* __restrict__ bb1,
    const float* __restrict__ m1, const float* __restrict__ v1,
    const float* __restrict__ gin_eps, int layer, __bf16* __restrict__ h1)
{
    int tid = threadIdx.x;
    int wv = tid >> 6, lane = tid & 63;
    int bm = blockIdx.x * 64 + wv * 16;
    int m = lane & 15, q = lane >> 4;
    int row = bm + m;
    bool valid = row < N_NODES;
    int rowc = valid ? row : 0;
    float eps1 = 1.0f + gin_eps[layer];

    // lane owns row m, channels [ks*32 + q*8, +8) for ks=0..3  (32 floats)
    const __bf16* base = xb + (size_t)rowc * 128 + q * 8;
    float acc[32];
    {
        bf16x8 s0 = *(const bf16x8*)(base);
        bf16x8 s1 = *(const bf16x8*)(base + 32);
        bf16x8 s2 = *(const bf16x8*)(base + 64);
        bf16x8 s3 = *(const bf16x8*)(base + 96);
        #pragma unroll
        for (int j = 0; j < 8; j++) {
            acc[j]      = eps1 * (float)s0[j];
            acc[8 + j]  = eps1 * (float)s1[j];
            acc[16 + j] = eps1 * (float)s2[j];
            acc[24 + j] = eps1 * (float)s3[j];
        }
    }
    int e0 = rowptr[rowc];
    int e1 = valid ? rowptr[rowc + 1] : e0;
    int e = e0;
    for (; e + 2 <= e1; e += 2) {
        int i0 = eidx[e], i1 = eidx[e + 1];
        const __bf16* p0 = xb + (size_t)i0 * 128 + q * 8;
        const __bf16* p1 = xb + (size_t)i1 * 128 + q * 8;
        bf16x8 a0 = *(const bf16x8*)(p0);
        bf16x8 a1 = *(const bf16x8*)(p0 + 32);
        bf16x8 a2 = *(const bf16x8*)(p0 + 64);
        bf16x8 a3 = *(const bf16x8*)(p0 + 96);
        bf16x8 c0 = *(const bf16x8*)(p1);
        bf16x8 c1 = *(const bf16x8*)(p1 + 32);
        bf16x8 c2 = *(const bf16x8*)(p1 + 64);
        bf16x8 c3 = *(const bf16x8*)(p1 + 96);
        #pragma unroll
        for (int j = 0; j < 8; j++) {
            acc[j]      += (float)a0[j] + (float)c0[j];
            acc[8 + j]  += (float)a1[j] + (float)c1[j];
            acc[16 + j] += (float)a2[j] + (float)c2[j];
            acc[24 + j] += (float)a3[j] + (float)c3[j];
        }
    }
    if (e < e1) {
        int i0 = eidx[e];
        const __bf16* p0 = xb + (size_t)i0 * 128 + q * 8;
        bf16x8 a0 = *(const bf16x8*)(p0);
        bf16x8 a1 = *(const bf16x8*)(p0 + 32);
        bf16x8 a2 = *(const bf16x8*)(p0 + 64);
        bf16x8 a3 = *(const bf16x8*)(p0 + 96);
        #pragma unroll
        for (int j = 0; j < 8; j++) {
            acc[j]      += (float)a0[j];
            acc[8 + j]  += (float)a1[j];
            acc[16 + j] += (float)a2[j];
            acc[24 + j] += (float)a3[j];
        }
    }

    bf16x8 af[4];
    #pragma unroll
    for (int ks = 0; ks < 4; ks++) {
        #pragma unroll
        for (int j = 0; j < 8; j++) af[ks][j] = (__bf16)acc[ks * 8 + j];
    }

    const __bf16* pB = w1S + q * 2048 + m * 8;
    int rq = q * 4;
    for (int nt = 0; nt < 16; nt++) {
        f32x4 o = {0.f, 0.f, 0.f, 0.f};
        #pragma unroll
        for (int ks = 0; ks < 4; ks++) {
            bf16x8 bfrag = *(const bf16x8*)(pB + nt * 128 + ks * 8192);
            o = __builtin_amdgcn_mfma_f32_16x16x32_bf16(af[ks], bfrag, o, 0, 0, 0);
        }
        int n = nt * 16 + m;
        float s = g1[n] * rsqrtf(v1[n] + BN_EPS);
        float cc = (b1[n] - m1[n]) * s + bb1[n];
        #pragma unroll
        for (int r2 = 0; r2 < 4; r2++) {
            int orow = bm + rq + r2;
            if (orow < N_NODES) {
                float z = o[r2] * s + cc;
                h1[(size_t)orow * 256 + n] = (__bf16)fmaxf(z, 0.0f);
            }
        }
    }
}

// GEMM2: x_out = relu(bn2(h1 @ w2 + b2))  [M x 128], K=256, LDS-free
__global__ __launch_bounds__(256) void gin_gemm2(
    const __bf16* __restrict__ h1, const __bf16* __restrict__ w2S,
    const float* __restrict__ b2, const float* __restrict__ g2, const float* __restrict__ bb2,
    const float* __restrict__ m2, const float* __restrict__ v2, __bf16* __restrict__ xout)
{
    int tid = threadIdx.x;
    int wv = tid >> 6, lane = tid & 63;
    int bm = blockIdx.x * 64 + wv * 16;
    int m = lane & 15, q = lane >> 4;
    int row = bm + m;
    int rowc = (row < N_NODES) ? row : (N_NODES - 1);

    const __bf16* arow = h1 + (size_t)rowc * 256 + q * 8;
    bf16x8 af[8];
    #pragma unroll
    for (int ks = 0; ks < 8; ks++) af[ks] = *(const bf16x8*)(arow + ks * 32);

    const __bf16* pB = w2S + q * 1024 + m * 8;
    int rq = q * 4;
    for (int nt = 0; nt < 8; nt++) {
        f32x4 o = {0.f, 0.f, 0.f, 0.f};
        #pragma unroll
        for (int ks = 0; ks < 8; ks++) {
            bf16x8 bfrag = *(const bf16x8*)(pB + nt * 128 + ks * 4096);
            o = __builtin_amdgcn_mfma_f32_16x16x32_bf16(af[ks], bfrag, o, 0, 0, 0);
        }
        int n = nt * 16 + m;
        float s = g2[n] * rsqrtf(v2[n] + BN_EPS);
        float cc = (b2[n] - m2[n]) * s + bb2[n];
        #pragma unroll
        for (int r2 = 0; r2 < 4; r2++) {
            int orow = bm + rq + r2;
            if (orow < N_NODES) {
                float z = o[r2] * s + cc;
                xout[(size_t)orow * 128 + n] = (__bf16)fmaxf(z, 0.0f);
            }
        }
    }
}

// ---------------- pooling + head ----------------
// batch is sorted: accumulate runs in registers, atomic only at run boundaries.
__global__ void pool_kernel(const __bf16* __restrict__ xb, const int* __restrict__ batch,
                            float* __restrict__ pooled) {
    int c = threadIdx.x;               // 128 channels
    int n0 = blockIdx.x * 64;
    if (n0 >= N_NODES) return;
    int cur = batch[n0];
    float acc = 0.0f;
    int nend = (n0 + 64 < N_NODES) ? n0 + 64 : N_NODES;
    for (int node = n0; node < nend; node++) {
        int b = batch[node];
        if (b != cur) {
            unsafeAtomicAdd(&pooled[cur * 128 + c], acc);
            acc = 0.0f; cur = b;
        }
        acc += (float)xb[(size_t)node * 128 + c];
    }
    unsafeAtomicAdd(&pooled[cur * 128 + c], acc);
}

__global__ void final_kernel(const float* __restrict__ pooled,
                             const float* __restrict__ lw1, const float* __restrict__ lb1,
                             const float* __restrict__ g3, const float* __restrict__ b3,
                             const float* __restrict__ m3, const float* __restrict__ v3,
                             const float* __restrict__ lw2, const float* __restrict__ lb2,
                             float* __restrict__ out) {
    int gid = blockIdx.x;
    int t = threadIdx.x;
    __shared__ float p[128], hs[128], lg[10];
    p[t] = pooled[gid * 128 + t];
    __syncthreads();
    float z = lb1[t];
    #pragma unroll 4
    for (int k = 0; k < 128; k++) z += p[k] * lw1[k * 128 + t];
    float h = (z - m3[t]) * rsqrtf(v3[t] + BN_EPS) * g3[t] + b3[t];
    hs[t] = fmaxf(h, 0.0f);
    __syncthreads();
    if (t < 10) {
        float o = lb2[t];
        #pragma unroll 4
        for (int k = 0; k < 128; k++) o += hs[k] * lw2[k * 10 + t];
        lg[t] = o;
    }
    __syncthreads();
    if (t < 10) {
        float mx = lg[0];
        for (int j = 1; j < 10; j++) mx = fmaxf(mx, lg[j]);
        float sum = 0.0f;
        for (int j = 0; j < 10; j++) sum += expf(lg[j] - mx);
        out[gid * 10 + t] = lg[t] - mx - logf(sum);
    }
}

// ---------------- launch ----------------

extern "C" void kernel_launch(void* const* d_in, const int* in_sizes, int n_in,
                              void* d_out, int out_size, void* d_ws, size_t ws_size,
                              hipStream_t stream) {
    (void)in_sizes; (void)n_in; (void)out_size; (void)ws_size;
    const float* x      = (const float*)d_in[0];
    const int*   ei     = (const int*)d_in[1];
    const int*   srcv   = ei;
    const int*   dstv   = ei + N_EDGES;
    const int*   batch  = (const int*)d_in[2];
    const float* w1     = (const float*)d_in[3];
    const float* b1     = (const float*)d_in[4];
    const float* bn1_g  = (const float*)d_in[5];
    const float* bn1_b  = (const float*)d_in[6];
    const float* bn1_m  = (const float*)d_in[7];
    const float* bn1_v  = (const float*)d_in[8];
    const float* geps   = (const float*)d_in[9];
    const float* w2     = (const float*)d_in[10];
    const float* b2     = (const float*)d_in[11];
    const float* bn2_g  = (const float*)d_in[12];
    const float* bn2_b  = (const float*)d_in[13];
    const float* bn2_m  = (const float*)d_in[14];
    const float* bn2_v  = (const float*)d_in[15];
    const float* lw1    = (const float*)d_in[16];
    const float* lb1    = (const float*)d_in[17];
    const float* g3     = (const float*)d_in[18];
    const float* b3     = (const float*)d_in[19];
    const float* m3     = (const float*)d_in[20];
    const float* v3     = (const float*)d_in[21];
    const float* lw2    = (const float*)d_in[22];
    const float* lb2    = (const float*)d_in[23];
    float* out = (float*)d_out;

    char* ws = (char*)d_ws;
    __bf16* xb    = (__bf16*)(ws + 0);
    __bf16* h1    = (__bf16*)(ws + 25600000);
    __bf16* w1S   = (__bf16*)(ws + 76800000);
    __bf16* w2S   = (__bf16*)(ws + 77062144);
    int*    deg   = (int*)   (ws + 77324288);
    int*    part  = (int*)   (ws + 77724288);
    int*    rowp  = (int*)   (ws + 78124288);
    int*    curs  = (int*)   (ws + 78524304);
    int*    eidx  = (int*)   (ws + 78924304);
    int*    bsum  = (int*)   (ws + 85324304);
    float*  pooled= (float*) (ws + 85326352);

    (void)hipMemsetAsync(deg, 0, N_NODES * sizeof(int), stream);
    (void)hipMemsetAsync(pooled, 0, N_GRAPHS * 128 * sizeof(float), stream);

    conv_x_kernel<<<(N_NODES * 128 / 4 + 255) / 256, 256, 0, stream>>>(x, xb);
    conv_w_kernel<<<(4 * 128 * 256 + 255) / 256, 256, 0, stream>>>(w1, w2, w1S, w2S);
    count_deg_kernel<<<(N_EDGES + 255) / 256, 256, 0, stream>>>(dstv, deg);

    int nb = (N_NODES + 255) / 256;  // 391
    scan_blocks_kernel<<<nb, 256, 0, stream>>>(deg, part, bsum, N_NODES);
    scan_bsums_kernel<<<1, 512, 0, stream>>>(bsum, nb);
    add_offsets_kernel<<<nb, 256, 0, stream>>>(part, bsum, rowp, N_NODES);
    init_cursor_kernel<<<(N_NODES + 255) / 256, 256, 0, stream>>>(rowp, curs);
    fill_eidx_kernel<<<(N_EDGES + 255) / 256, 256, 0, stream>>>(srcv, dstv, curs, eidx);

    int mblocks = (N_NODES + 63) / 64;  // 1563
    for (int l = 0; l < 4; l++) {
        gin_gemm1<<<mblocks, 256, 0, stream>>>(
            xb, rowp, eidx, w1S + l * 32768,
            b1 + l * 256, bn1_g + l * 256, bn1_b + l * 256, bn1_m + l * 256, bn1_v + l * 256,
            geps, l, h1);
        gin_gemm2<<<mblocks, 256, 0, stream>>>(
            h1, w2S + l * 32768,
            b2 + l * 128, bn2_g + l * 128, bn2_b + l * 128, bn2_m + l * 128, bn2_v + l * 128,
            xb);
    }

    pool_kernel<<<(N_NODES + 63) / 64, 128, 0, stream>>>(xb, batch, pooled);
    final_kernel<<<N_GRAPHS, 128, 0, stream>>>(pooled, lw1, lb1, g3, b3, m3, v3, lw2, lb2, out);
}

// Round 4
// 793.727 us; speedup vs baseline: 1.7728x; 1.1056x over previous
//
#include <hip/hip_runtime.h>

#define N_NODES 100000
#define N_EDGES 1600000
#define N_GRAPHS 512
#define BN_EPS 1e-5f
#define NB 98          // buckets = dst>>10  (100000/1024 -> 0..97)
#define NBLK 256       // binning blocks
#define EPB 6250       // edges per binning block (256*6250 = 1.6M)

typedef __bf16 bf16x8 __attribute__((ext_vector_type(8)));
typedef __bf16 bf16x4 __attribute__((ext_vector_type(4)));
typedef float  f32x4  __attribute__((ext_vector_type(4)));

// ---------------- small prep kernels ----------------

__global__ void conv_x_kernel(const float* __restrict__ x, __bf16* __restrict__ xb) {
    int i = blockIdx.x * 256 + threadIdx.x;            // one per 4 elems
    if (i < (N_NODES * 128) / 4) {
        float4 v = ((const float4*)x)[i];
        bf16x4 o;
        o[0] = (__bf16)v.x; o[1] = (__bf16)v.y; o[2] = (__bf16)v.z; o[3] = (__bf16)v.w;
        ((bf16x4*)xb)[i] = o;
    }
}

// Swizzled fragment-order weights:
// w1:[4][128][256] -> w1S: elem = l*32768 + (k>>3)*2048 + n*8 + (k&7)
// w2:[4][256][128] -> w2S: elem = l*32768 + (k>>3)*1024 + n*8 + (k&7)
__global__ void conv_w_kernel(const float* __restrict__ w1, const float* __restrict__ w2,
                              __bf16* __restrict__ w1S, __bf16* __restrict__ w2S) {
    int i = blockIdx.x * 256 + threadIdx.x;
    if (i < 4 * 128 * 256) {
        int l = i >> 15, r = i & 32767;
        int k = r >> 8, n = r & 255;
        w1S[(l << 15) + (k >> 3) * 2048 + n * 8 + (k & 7)] = (__bf16)w1[i];
        int k2 = r >> 7, n2 = r & 127;
        w2S[(l << 15) + (k2 >> 3) * 1024 + n2 * 8 + (k2 & 7)] = (__bf16)w2[i];
    }
}

// node degrees (global atomics) + per-(block,bucket) histogram (LDS)
__global__ __launch_bounds__(256) void count_kernel(const int* __restrict__ dstv,
                                                    int* __restrict__ deg, int* __restrict__ bh) {
    __shared__ int lh[NB];
    int t = threadIdx.x, blk = blockIdx.x;
    if (t < NB) lh[t] = 0;
    __syncthreads();
    int base = blk * EPB;
    int lim = base + EPB;
    for (int e = base + t; e < lim; e += 256) {
        int d = dstv[e];
        atomicAdd(&deg[d], 1);
        atomicAdd(&lh[d >> 10], 1);
    }
    __syncthreads();
    if (t < NB) bh[blk * NB + t] = lh[t];
}

// node-degree -> rowptr scan chain (unchanged)
__global__ void scan_blocks_kernel(const int* __restrict__ deg, int* __restrict__ partial,
                                   int* __restrict__ bsums, int n) {
    __shared__ int s[256];
    int t = threadIdx.x;
    int i = blockIdx.x * 256 + t;
    int v = (i < n) ? deg[i] : 0;
    s[t] = v; __syncthreads();
    for (int off = 1; off < 256; off <<= 1) {
        int x = (t >= off) ? s[t - off] : 0;
        __syncthreads();
        s[t] += x;
        __syncthreads();
    }
    if (i < n) partial[i] = s[t];
    if (t == 255) bsums[blockIdx.x] = s[255];
}

__global__ void scan_bsums_kernel(int* __restrict__ bsums, int nb) {
    __shared__ int s[512];
    int t = threadIdx.x;
    s[t] = (t < nb) ? bsums[t] : 0; __syncthreads();
    for (int off = 1; off < 512; off <<= 1) {
        int x = (t >= off) ? s[t - off] : 0;
        __syncthreads();
        s[t] += x;
        __syncthreads();
    }
    if (t < nb) bsums[t] = s[t];   // inclusive
}

__global__ void add_offsets_kernel(const int* __restrict__ partial, const int* __restrict__ bsums,
                                   int* __restrict__ rowptr, int n) {
    int i = blockIdx.x * 256 + threadIdx.x;
    int add = (blockIdx.x > 0) ? bsums[blockIdx.x - 1] : 0;
    if (i < n) rowptr[i + 1] = partial[i] + add;
    if (i == 0) rowptr[0] = 0;
}

// per-bucket column scan over blocks: offs[blk][b] = sum_{blk'<blk} bh[blk'][b]
__global__ void scan_col_kernel(const int* __restrict__ bh, int* __restrict__ offs,
                                int* __restrict__ bsz) {
    int b = blockIdx.x;            // 0..NB-1
    int t = threadIdx.x;           // 0..255
    __shared__ int s[256];
    int v = bh[t * NB + b];
    s[t] = v; __syncthreads();
    for (int off = 1; off < 256; off <<= 1) {
        int x = (t >= off) ? s[t - off] : 0;
        __syncthreads();
        s[t] += x;
        __syncthreads();
    }
    offs[t * NB + b] = s[t] - v;   // exclusive
    if (t == 255) bsz[b] = s[255];
}

__global__ void scan_base_kernel(const int* __restrict__ bsz, int* __restrict__ bktbase) {
    __shared__ int s[128];
    int t = threadIdx.x;
    int v = (t < NB) ? bsz[t] : 0;
    s[t] = v; __syncthreads();
    for (int off = 1; off < 128; off <<= 1) {
        int x = (t >= off) ? s[t - off] : 0;
        __syncthreads();
        s[t] += x;
        __syncthreads();
    }
    if (t < NB) bktbase[t + 1] = s[t];
    if (t == 0) bktbase[0] = 0;
}

// deterministic bucket placement: pairs[p] = (localdst<<17) | src
__global__ __launch_bounds__(256) void bin_place_kernel(
    const int* __restrict__ srcv, const int* __restrict__ dstv,
    const int* __restrict__ offs, const int* __restrict__ bktbase,
    unsigned int* __restrict__ pairs) {
    __shared__ int lcur[NB];
    int t = threadIdx.x, blk = blockIdx.x;
    if (t < NB) lcur[t] = bktbase[t] + offs[blk * NB + t];
    __syncthreads();
    int base = blk * EPB;
    int lim = base + EPB;
    for (int e = base + t; e < lim; e += 256) {
        int d = dstv[e];
        int src = srcv[e];
        int b = d >> 10;
        int p = atomicAdd(&lcur[b], 1);
        pairs[p] = ((unsigned int)(d & 1023) << 17) | (unsigned int)src;
    }
}

// one block per bucket: scatter window is 1 CU -> lines written back once
__global__ __launch_bounds__(256) void fill2_kernel(
    const unsigned int* __restrict__ pairs, const int* __restrict__ bktbase,
    const int* __restrict__ rowp, int* __restrict__ eidx) {
    __shared__ int lcur[1024];
    int b = blockIdx.x;
    int t = threadIdx.x;
    int node0 = b << 10;
    int nn = (node0 + 1024 <= N_NODES) ? 1024 : (N_NODES - node0);
    for (int i = t; i < nn; i += 256) lcur[i] = rowp[node0 + i];
    __syncthreads();
    int e0 = bktbase[b], e1 = bktbase[b + 1];
    for (int e = e0 + t; e < e1; e += 256) {
        unsigned int u = pairs[e];
        int ld = (int)(u >> 17);
        int src = (int)(u & 0x1FFFF);
        int p = atomicAdd(&lcur[ld], 1);
        eidx[p] = src;
    }
}

// ---------------- fused GIN layer GEMMs (LDS-free) ----------------
// GEMM1: per-lane register gather of A = (1+eps)*x + sum_neighbors(x), then
// MFMA vs w1S read straight from global (L1/L2-resident, coalesced frag order).

__global__ __launch_bounds__(256) void gin_gemm1(
    const __bf16* __restrict__ xb, const int* __restrict__ rowptr, const int* __restrict__ eidx,
    const __bf16* __restrict__ w1S, const float* __restrict__ b1,
    const float* __restrict__ g1, const float* __restrict__ bb1,
    const float* __restrict__ m1, const float* __restrict__ v1,
    const float* __restrict__ gin_eps, int layer, __bf16* __restrict__ h1)
{
    int tid = threadIdx.x;
    int wv = tid >> 6, lane = tid & 63;
    int bm = blockIdx.x * 64 + wv * 16;
    int m = lane & 15, q = lane >> 4;
    int row = bm + m;
    bool valid = row < N_NODES;
    int rowc = valid ? row : 0;
    float eps1 = 1.0f + gin_eps[layer];
    int qo = q * 8;

    // lane owns row m, channels [ks*32 + q*8, +8) for ks=0..3  (32 floats)
    const __bf16* base = xb + (size_t)rowc * 128 + qo;
    float acc[32];
    {
        bf16x8 s0 = *(const bf16x8*)(base);
        bf16x8 s1 = *(const bf16x8*)(base + 32);
        bf16x8 s2 = *(const bf16x8*)(base + 64);
        bf16x8 s3 = *(const bf16x8*)(base + 96);
        #pragma unroll
        for (int j = 0; j < 8; j++) {
            acc[j]      = eps1 * (float)s0[j];
            acc[8 + j]  = eps1 * (float)s1[j];
            acc[16 + j] = eps1 * (float)s2[j];
            acc[24 + j] = eps1 * (float)s3[j];
        }
    }
    int e0 = rowptr[rowc];
    int e1 = valid ? rowptr[rowc + 1] : e0;
    int e = e0;
    for (; e + 4 <= e1; e += 4) {
        int i0 = eidx[e], i1 = eidx[e + 1], i2 = eidx[e + 2], i3 = eidx[e + 3];
        const __bf16* p0 = xb + (size_t)i0 * 128 + qo;
        const __bf16* p1 = xb + (size_t)i1 * 128 + qo;
        const __bf16* p2 = xb + (size_t)i2 * 128 + qo;
        const __bf16* p3 = xb + (size_t)i3 * 128 + qo;
        bf16x8 v0[4], v1[4], v2[4], v3[4];
        #pragma unroll
        for (int k = 0; k < 4; k++) {
            v0[k] = *(const bf16x8*)(p0 + k * 32);
            v1[k] = *(const bf16x8*)(p1 + k * 32);
            v2[k] = *(const bf16x8*)(p2 + k * 32);
            v3[k] = *(const bf16x8*)(p3 + k * 32);
        }
        #pragma unroll
        for (int k = 0; k < 4; k++) {
            #pragma unroll
            for (int j = 0; j < 8; j++) {
                acc[k * 8 + j] += ((float)v0[k][j] + (float)v1[k][j])
                                + ((float)v2[k][j] + (float)v3[k][j]);
            }
        }
    }
    for (; e < e1; ++e) {
        const __bf16* p0 = xb + (size_t)eidx[e] * 128 + qo;
        bf16x8 a0 = *(const bf16x8*)(p0);
        bf16x8 a1 = *(const bf16x8*)(p0 + 32);
        bf16x8 a2 = *(const bf16x8*)(p0 + 64);
        bf16x8 a3 = *(const bf16x8*)(p0 + 96);
        #pragma unroll
        for (int j = 0; j < 8; j++) {
            acc[j]      += (float)a0[j];
            acc[8 + j]  += (float)a1[j];
            acc[16 + j] += (float)a2[j];
            acc[24 + j] += (float)a3[j];
        }
    }

    bf16x8 af[4];
    #pragma unroll
    for (int ks = 0; ks < 4; ks++) {
        #pragma unroll
        for (int j = 0; j < 8; j++) af[ks][j] = (__bf16)acc[ks * 8 + j];
    }

    const __bf16* pB = w1S + q * 2048 + m * 8;
    int rq = q * 4;
    for (int nt = 0; nt < 16; nt++) {
        f32x4 o = {0.f, 0.f, 0.f, 0.f};
        #pragma unroll
        for (int ks = 0; ks < 4; ks++) {
            bf16x8 bfrag = *(const bf16x8*)(pB + nt * 128 + ks * 8192);
            o = __builtin_amdgcn_mfma_f32_16x16x32_bf16(af[ks], bfrag, o, 0, 0, 0);
        }
        int n = nt * 16 + m;
        float s = g1[n] * rsqrtf(v1[n] + BN_EPS);
        float cc = (b1[n] - m1[n]) * s + bb1[n];
        #pragma unroll
        for (int r2 = 0; r2 < 4; r2++) {
            int orow = bm + rq + r2;
            if (orow < N_NODES) {
                float z = o[r2] * s + cc;
                h1[(size_t)orow * 256 + n] = (__bf16)fmaxf(z, 0.0f);
            }
        }
    }
}

// GEMM2: x_out = relu(bn2(h1 @ w2 + b2))  [M x 128], K=256, LDS-free
__global__ __launch_bounds__(256) void gin_gemm2(
    const __bf16* __restrict__ h1, const __bf16* __restrict__ w2S,
    const float* __restrict__ b2, const float* __restrict__ g2, const float* __restrict__ bb2,
    const float* __restrict__ m2, const float* __restrict__ v2, __bf16* __restrict__ xout)
{
    int tid = threadIdx.x;
    int wv = tid >> 6, lane = tid & 63;
    int bm = blockIdx.x * 64 + wv * 16;
    int m = lane & 15, q = lane >> 4;
    int row = bm + m;
    int rowc = (row < N_NODES) ? row : (N_NODES - 1);

    const __bf16* arow = h1 + (size_t)rowc * 256 + q * 8;
    bf16x8 af[8];
    #pragma unroll
    for (int ks = 0; ks < 8; ks++) af[ks] = *(const bf16x8*)(arow + ks * 32);

    const __bf16* pB = w2S + q * 1024 + m * 8;
    int rq = q * 4;
    for (int nt = 0; nt < 8; nt++) {
        f32x4 o = {0.f, 0.f, 0.f, 0.f};
        #pragma unroll
        for (int ks = 0; ks < 8; ks++) {
            bf16x8 bfrag = *(const bf16x8*)(pB + nt * 128 + ks * 4096);
            o = __builtin_amdgcn_mfma_f32_16x16x32_bf16(af[ks], bfrag, o, 0, 0, 0);
        }
        int n = nt * 16 + m;
        float s = g2[n] * rsqrtf(v2[n] + BN_EPS);
        float cc = (b2[n] - m2[n]) * s + bb2[n];
        #pragma unroll
        for (int r2 = 0; r2 < 4; r2++) {
            int orow = bm + rq + r2;
            if (orow < N_NODES) {
                float z = o[r2] * s + cc;
                xout[(size_t)orow * 128 + n] = (__bf16)fmaxf(z, 0.0f);
            }
        }
    }
}

// ---------------- pooling + head ----------------
// batch is sorted: accumulate runs in registers, atomic only at run boundaries.
__global__ void pool_kernel(const __bf16* __restrict__ xb, const int* __restrict__ batch,
                            float* __restrict__ pooled) {
    int c = threadIdx.x;               // 128 channels
    int n0 = blockIdx.x * 64;
    if (n0 >= N_NODES) return;
    int cur = batch[n0];
    float acc = 0.0f;
    int nend = (n0 + 64 < N_NODES) ? n0 + 64 : N_NODES;
    for (int node = n0; node < nend; node++) {
        int b = batch[node];
        if (b != cur) {
            unsafeAtomicAdd(&pooled[cur * 128 + c], acc);
            acc = 0.0f; cur = b;
        }
        acc += (float)xb[(size_t)node * 128 + c];
    }
    unsafeAtomicAdd(&pooled[cur * 128 + c], acc);
}

__global__ void final_kernel(const float* __restrict__ pooled,
                             const float* __restrict__ lw1, const float* __restrict__ lb1,
                             const float* __restrict__ g3, const float* __restrict__ b3,
                             const float* __restrict__ m3, const float* __restrict__ v3,
                             const float* __restrict__ lw2, const float* __restrict__ lb2,
                             float* __restrict__ out) {
    int gid = blockIdx.x;
    int t = threadIdx.x;
    __shared__ float p[128], hs[128], lg[10];
    p[t] = pooled[gid * 128 + t];
    __syncthreads();
    float z = lb1[t];
    #pragma unroll 4
    for (int k = 0; k < 128; k++) z += p[k] * lw1[k * 128 + t];
    float h = (z - m3[t]) * rsqrtf(v3[t] + BN_EPS) * g3[t] + b3[t];
    hs[t] = fmaxf(h, 0.0f);
    __syncthreads();
    if (t < 10) {
        float o = lb2[t];
        #pragma unroll 4
        for (int k = 0; k < 128; k++) o += hs[k] * lw2[k * 10 + t];
        lg[t] = o;
    }
    __syncthreads();
    if (t < 10) {
        float mx = lg[0];
        for (int j = 1; j < 10; j++) mx = fmaxf(mx, lg[j]);
        float sum = 0.0f;
        for (int j = 0; j < 10; j++) sum += expf(lg[j] - mx);
        out[gid * 10 + t] = lg[t] - mx - logf(sum);
    }
}

// ---------------- launch ----------------

extern "C" void kernel_launch(void* const* d_in, const int* in_sizes, int n_in,
                              void* d_out, int out_size, void* d_ws, size_t ws_size,
                              hipStream_t stream) {
    (void)in_sizes; (void)n_in; (void)out_size; (void)ws_size;
    const float* x      = (const float*)d_in[0];
    const int*   ei     = (const int*)d_in[1];
    const int*   srcv   = ei;
    const int*   dstv   = ei + N_EDGES;
    const int*   batch  = (const int*)d_in[2];
    const float* w1     = (const float*)d_in[3];
    const float* b1     = (const float*)d_in[4];
    const float* bn1_g  = (const float*)d_in[5];
    const float* bn1_b  = (const float*)d_in[6];
    const float* bn1_m  = (const float*)d_in[7];
    const float* bn1_v  = (const float*)d_in[8];
    const float* geps   = (const float*)d_in[9];
    const float* w2     = (const float*)d_in[10];
    const float* b2     = (const float*)d_in[11];
    const float* bn2_g  = (const float*)d_in[12];
    const float* bn2_b  = (const float*)d_in[13];
    const float* bn2_m  = (const float*)d_in[14];
    const float* bn2_v  = (const float*)d_in[15];
    const float* lw1    = (const float*)d_in[16];
    const float* lb1    = (const float*)d_in[17];
    const float* g3     = (const float*)d_in[18];
    const float* b3     = (const float*)d_in[19];
    const float* m3     = (const float*)d_in[20];
    const float* v3     = (const float*)d_in[21];
    const float* lw2    = (const float*)d_in[22];
    const float* lb2    = (const float*)d_in[23];
    float* out = (float*)d_out;

    char* ws = (char*)d_ws;
    __bf16* xb    = (__bf16*)(ws + 0);                 // 25.6 MB
    __bf16* h1    = (__bf16*)(ws + 25600000);          // 51.2 MB (aliased below pre-GEMM)
    // --- aliases inside h1 region (dead once gemm1 layer-0 runs) ---
    unsigned int* pairs = (unsigned int*)(ws + 25600000);   // 6.4 MB
    int*    bh    = (int*)   (ws + 32000000);          // 256*98*4 = 100352
    int*    offs  = (int*)   (ws + 32100352);          // 100352
    int*    bbase = (int*)   (ws + 32200704);          // 99*4
    int*    bsz   = (int*)   (ws + 32201200);          // 98*4
    // --- persistent ---
    __bf16* w1S   = (__bf16*)(ws + 76800000);
    __bf16* w2S   = (__bf16*)(ws + 77062144);
    int*    deg   = (int*)   (ws + 77324288);
    int*    part  = (int*)   (ws + 77724288);
    int*    rowp  = (int*)   (ws + 78124288);
    int*    eidx  = (int*)   (ws + 78524304);
    int*    bsum  = (int*)   (ws + 84924304);
    float*  pooled= (float*) (ws + 84925888);

    (void)hipMemsetAsync(deg, 0, N_NODES * sizeof(int), stream);
    (void)hipMemsetAsync(pooled, 0, N_GRAPHS * 128 * sizeof(float), stream);

    conv_x_kernel<<<(N_NODES * 128 / 4 + 255) / 256, 256, 0, stream>>>(x, xb);
    conv_w_kernel<<<(4 * 128 * 256 + 255) / 256, 256, 0, stream>>>(w1, w2, w1S, w2S);

    // CSR build: degrees+bucket histograms, scans, deterministic binning, local fill
    count_kernel<<<NBLK, 256, 0, stream>>>(dstv, deg, bh);

    int nb = (N_NODES + 255) / 256;  // 391
    scan_blocks_kernel<<<nb, 256, 0, stream>>>(deg, part, bsum, N_NODES);
    scan_bsums_kernel<<<1, 512, 0, stream>>>(bsum, nb);
    add_offsets_kernel<<<nb, 256, 0, stream>>>(part, bsum, rowp, N_NODES);

    scan_col_kernel<<<NB, 256, 0, stream>>>(bh, offs, bsz);
    scan_base_kernel<<<1, 128, 0, stream>>>(bsz, bbase);
    bin_place_kernel<<<NBLK, 256, 0, stream>>>(srcv, dstv, offs, bbase, pairs);
    fill2_kernel<<<NB, 256, 0, stream>>>(pairs, bbase, rowp, eidx);

    int mblocks = (N_NODES + 63) / 64;  // 1563
    for (int l = 0; l < 4; l++) {
        gin_gemm1<<<mblocks, 256, 0, stream>>>(
            xb, rowp, eidx, w1S + l * 32768,
            b1 + l * 256, bn1_g + l * 256, bn1_b + l * 256, bn1_m + l * 256, bn1_v + l * 256,
            geps, l, h1);
        gin_gemm2<<<mblocks, 256, 0, stream>>>(
            h1, w2S + l * 32768,
            b2 + l * 128, bn2_g + l * 128, bn2_b + l * 128, bn2_m + l * 128, bn2_v + l * 128,
            xb);
    }

    pool_kernel<<<(N_NODES + 63) / 64, 128, 0, stream>>>(xb, batch, pooled);
    final_kernel<<<N_GRAPHS, 128, 0, stream>>>(pooled, lw1, lb1, g3, b3, m3, v3, lw2, lb2, out);
}

// Round 5
// 709.933 us; speedup vs baseline: 1.9821x; 1.1180x over previous
//
#include <hip/hip_runtime.h>

#define N_NODES 100000
#define N_EDGES 1600000
#define N_GRAPHS 512
#define BN_EPS 1e-5f
#define NB 98          // buckets = dst>>10  (100000/1024 -> 0..97)
#define NBLK 256       // binning blocks
#define EPB 6250       // edges per binning block (256*6250 = 1.6M)

typedef __bf16 bf16x8 __attribute__((ext_vector_type(8)));
typedef __bf16 bf16x4 __attribute__((ext_vector_type(4)));
typedef float  f32x4  __attribute__((ext_vector_type(4)));

// ---------------- small prep kernels ----------------

__global__ void conv_x_kernel(const float* __restrict__ x, __bf16* __restrict__ xb) {
    int i = blockIdx.x * 256 + threadIdx.x;            // one per 4 elems
    if (i < (N_NODES * 128) / 4) {
        float4 v = ((const float4*)x)[i];
        bf16x4 o;
        o[0] = (__bf16)v.x; o[1] = (__bf16)v.y; o[2] = (__bf16)v.z; o[3] = (__bf16)v.w;
        ((bf16x4*)xb)[i] = o;
    }
}

// Swizzled fragment-order weights:
// w1:[4][128][256] -> w1S: elem = l*32768 + (k>>3)*2048 + n*8 + (k&7)
// w2:[4][256][128] -> w2S: elem = l*32768 + (k>>3)*1024 + n*8 + (k&7)
__global__ void conv_w_kernel(const float* __restrict__ w1, const float* __restrict__ w2,
                              __bf16* __restrict__ w1S, __bf16* __restrict__ w2S) {
    int i = blockIdx.x * 256 + threadIdx.x;
    if (i < 4 * 128 * 256) {
        int l = i >> 15, r = i & 32767;
        int k = r >> 8, n = r & 255;
        w1S[(l << 15) + (k >> 3) * 2048 + n * 8 + (k & 7)] = (__bf16)w1[i];
        int k2 = r >> 7, n2 = r & 127;
        w2S[(l << 15) + (k2 >> 3) * 1024 + n2 * 8 + (k2 & 7)] = (__bf16)w2[i];
    }
}

// node degrees (global atomics) + per-(block,bucket) histogram (LDS)
__global__ __launch_bounds__(256) void count_kernel(const int* __restrict__ dstv,
                                                    int* __restrict__ deg, int* __restrict__ bh) {
    __shared__ int lh[NB];
    int t = threadIdx.x, blk = blockIdx.x;
    if (t < NB) lh[t] = 0;
    __syncthreads();
    int base = blk * EPB;
    int lim = base + EPB;
    for (int e = base + t; e < lim; e += 256) {
        int d = dstv[e];
        atomicAdd(&deg[d], 1);
        atomicAdd(&lh[d >> 10], 1);
    }
    __syncthreads();
    if (t < NB) bh[blk * NB + t] = lh[t];
}

__global__ void scan_blocks_kernel(const int* __restrict__ deg, int* __restrict__ partial,
                                   int* __restrict__ bsums, int n) {
    __shared__ int s[256];
    int t = threadIdx.x;
    int i = blockIdx.x * 256 + t;
    int v = (i < n) ? deg[i] : 0;
    s[t] = v; __syncthreads();
    for (int off = 1; off < 256; off <<= 1) {
        int x = (t >= off) ? s[t - off] : 0;
        __syncthreads();
        s[t] += x;
        __syncthreads();
    }
    if (i < n) partial[i] = s[t];
    if (t == 255) bsums[blockIdx.x] = s[255];
}

__global__ void scan_bsums_kernel(int* __restrict__ bsums, int nb) {
    __shared__ int s[512];
    int t = threadIdx.x;
    s[t] = (t < nb) ? bsums[t] : 0; __syncthreads();
    for (int off = 1; off < 512; off <<= 1) {
        int x = (t >= off) ? s[t - off] : 0;
        __syncthreads();
        s[t] += x;
        __syncthreads();
    }
    if (t < nb) bsums[t] = s[t];   // inclusive
}

__global__ void add_offsets_kernel(const int* __restrict__ partial, const int* __restrict__ bsums,
                                   int* __restrict__ rowptr, int n) {
    int i = blockIdx.x * 256 + threadIdx.x;
    int add = (blockIdx.x > 0) ? bsums[blockIdx.x - 1] : 0;
    if (i < n) rowptr[i + 1] = partial[i] + add;
    if (i == 0) rowptr[0] = 0;
}

// per-bucket column scan over blocks: offs[blk][b] = sum_{blk'<blk} bh[blk'][b]
__global__ void scan_col_kernel(const int* __restrict__ bh, int* __restrict__ offs,
                                int* __restrict__ bsz) {
    int b = blockIdx.x;            // 0..NB-1
    int t = threadIdx.x;           // 0..255
    __shared__ int s[256];
    int v = bh[t * NB + b];
    s[t] = v; __syncthreads();
    for (int off = 1; off < 256; off <<= 1) {
        int x = (t >= off) ? s[t - off] : 0;
        __syncthreads();
        s[t] += x;
        __syncthreads();
    }
    offs[t * NB + b] = s[t] - v;   // exclusive
    if (t == 255) bsz[b] = s[255];
}

__global__ void scan_base_kernel(const int* __restrict__ bsz, int* __restrict__ bktbase) {
    __shared__ int s[128];
    int t = threadIdx.x;
    int v = (t < NB) ? bsz[t] : 0;
    s[t] = v; __syncthreads();
    for (int off = 1; off < 128; off <<= 1) {
        int x = (t >= off) ? s[t - off] : 0;
        __syncthreads();
        s[t] += x;
        __syncthreads();
    }
    if (t < NB) bktbase[t + 1] = s[t];
    if (t == 0) bktbase[0] = 0;
}

// deterministic bucket placement: pairs[p] = (localdst<<17) | src
__global__ __launch_bounds__(256) void bin_place_kernel(
    const int* __restrict__ srcv, const int* __restrict__ dstv,
    const int* __restrict__ offs, const int* __restrict__ bktbase,
    unsigned int* __restrict__ pairs) {
    __shared__ int lcur[NB];
    int t = threadIdx.x, blk = blockIdx.x;
    if (t < NB) lcur[t] = bktbase[t] + offs[blk * NB + t];
    __syncthreads();
    int base = blk * EPB;
    int lim = base + EPB;
    for (int e = base + t; e < lim; e += 256) {
        int d = dstv[e];
        int src = srcv[e];
        int b = d >> 10;
        int p = atomicAdd(&lcur[b], 1);
        pairs[p] = ((unsigned int)(d & 1023) << 17) | (unsigned int)src;
    }
}

// one block per bucket: scatter window is 1 CU -> lines written back once
__global__ __launch_bounds__(256) void fill2_kernel(
    const unsigned int* __restrict__ pairs, const int* __restrict__ bktbase,
    const int* __restrict__ rowp, int* __restrict__ eidx) {
    __shared__ int lcur[1024];
    int b = blockIdx.x;
    int t = threadIdx.x;
    int node0 = b << 10;
    int nn = (node0 + 1024 <= N_NODES) ? 1024 : (N_NODES - node0);
    for (int i = t; i < nn; i += 256) lcur[i] = rowp[node0 + i];
    __syncthreads();
    int e0 = bktbase[b], e1 = bktbase[b + 1];
    for (int e = e0 + t; e < e1; e += 256) {
        unsigned int u = pairs[e];
        int ld = (int)(u >> 17);
        int src = (int)(u & 0x1FFFF);
        int p = atomicAdd(&lcur[ld], 1);
        eidx[p] = src;
    }
}

// ---------------- fully fused GIN layer ----------------
// Per wave: gather+agg 16 rows (regs) -> MFMA1+bn1+relu -> per-wave LDS tile
// (C-layout -> A-layout remap) -> MFMA2+bn2+relu -> xout. No __syncthreads:
// waves flow independently; LDS RAW is same-wave, ordered by lgkmcnt.
// NOTE: xin/xout must be distinct buffers (blocks overlap across the grid).

__global__ __launch_bounds__(256) void gin_layer(
    const __bf16* __restrict__ xin, const int* __restrict__ rowptr, const int* __restrict__ eidx,
    const __bf16* __restrict__ w1S, const __bf16* __restrict__ w2S,
    const float* __restrict__ b1, const float* __restrict__ g1, const float* __restrict__ bb1,
    const float* __restrict__ m1, const float* __restrict__ v1,
    const float* __restrict__ b2, const float* __restrict__ g2, const float* __restrict__ bb2,
    const float* __restrict__ m2, const float* __restrict__ v2,
    const float* __restrict__ gin_eps, int layer, __bf16* __restrict__ xout)
{
    __shared__ __align__(16) __bf16 hs[64 * 264];   // 33.8 KB, stride 264: 2-way banks (free)
    int tid = threadIdx.x;
    int wv = tid >> 6, lane = tid & 63;
    int bm = blockIdx.x * 64 + wv * 16;
    int m = lane & 15, q = lane >> 4;
    int row = bm + m;
    bool valid = row < N_NODES;
    int rowc = valid ? row : 0;
    float eps1 = 1.0f + gin_eps[layer];
    int qo = q * 8;

    // ---- phase 0: per-lane register gather: row m, channels ks*32+q*8 ----
    const __bf16* base = xin + (size_t)rowc * 128 + qo;
    float acc[32];
    {
        bf16x8 s0 = *(const bf16x8*)(base);
        bf16x8 s1 = *(const bf16x8*)(base + 32);
        bf16x8 s2 = *(const bf16x8*)(base + 64);
        bf16x8 s3 = *(const bf16x8*)(base + 96);
        #pragma unroll
        for (int j = 0; j < 8; j++) {
            acc[j]      = eps1 * (float)s0[j];
            acc[8 + j]  = eps1 * (float)s1[j];
            acc[16 + j] = eps1 * (float)s2[j];
            acc[24 + j] = eps1 * (float)s3[j];
        }
    }
    int e0 = rowptr[rowc];
    int e1 = valid ? rowptr[rowc + 1] : e0;
    int e = e0;
    for (; e + 4 <= e1; e += 4) {
        int i0 = eidx[e], i1 = eidx[e + 1], i2 = eidx[e + 2], i3 = eidx[e + 3];
        const __bf16* p0 = xin + (size_t)i0 * 128 + qo;
        const __bf16* p1 = xin + (size_t)i1 * 128 + qo;
        const __bf16* p2 = xin + (size_t)i2 * 128 + qo;
        const __bf16* p3 = xin + (size_t)i3 * 128 + qo;
        bf16x8 v0[4], v1r[4], v2r[4], v3r[4];
        #pragma unroll
        for (int k = 0; k < 4; k++) {
            v0[k]  = *(const bf16x8*)(p0 + k * 32);
            v1r[k] = *(const bf16x8*)(p1 + k * 32);
            v2r[k] = *(const bf16x8*)(p2 + k * 32);
            v3r[k] = *(const bf16x8*)(p3 + k * 32);
        }
        #pragma unroll
        for (int k = 0; k < 4; k++) {
            #pragma unroll
            for (int j = 0; j < 8; j++) {
                acc[k * 8 + j] += ((float)v0[k][j] + (float)v1r[k][j])
                                + ((float)v2r[k][j] + (float)v3r[k][j]);
            }
        }
    }
    for (; e < e1; ++e) {
        const __bf16* p0 = xin + (size_t)eidx[e] * 128 + qo;
        bf16x8 a0 = *(const bf16x8*)(p0);
        bf16x8 a1 = *(const bf16x8*)(p0 + 32);
        bf16x8 a2 = *(const bf16x8*)(p0 + 64);
        bf16x8 a3 = *(const bf16x8*)(p0 + 96);
        #pragma unroll
        for (int j = 0; j < 8; j++) {
            acc[j]      += (float)a0[j];
            acc[8 + j]  += (float)a1[j];
            acc[16 + j] += (float)a2[j];
            acc[24 + j] += (float)a3[j];
        }
    }

    bf16x8 af[4];
    #pragma unroll
    for (int ks = 0; ks < 4; ks++) {
        #pragma unroll
        for (int j = 0; j < 8; j++) af[ks][j] = (__bf16)acc[ks * 8 + j];
    }

    // ---- phase 1: MFMA1 + bn1 + relu -> per-wave LDS tile (16 x 256) ----
    const __bf16* pB = w1S + q * 2048 + m * 8;
    int rq = q * 4;
    int wrow0 = wv * 16;
    for (int nt = 0; nt < 16; nt++) {
        f32x4 o = {0.f, 0.f, 0.f, 0.f};
        #pragma unroll
        for (int ks = 0; ks < 4; ks++) {
            bf16x8 bfrag = *(const bf16x8*)(pB + nt * 128 + ks * 8192);
            o = __builtin_amdgcn_mfma_f32_16x16x32_bf16(af[ks], bfrag, o, 0, 0, 0);
        }
        int n = nt * 16 + m;
        float s = g1[n] * rsqrtf(v1[n] + BN_EPS);
        float cc = (b1[n] - m1[n]) * s + bb1[n];
        #pragma unroll
        for (int r2 = 0; r2 < 4; r2++) {
            float z = o[r2] * s + cc;
            hs[(wrow0 + rq + r2) * 264 + n] = (__bf16)fmaxf(z, 0.0f);
        }
    }

    // ---- phase 2: MFMA2 + bn2 + relu -> xout (A-frags from own LDS tile) ----
    bf16x8 af2[8];
    #pragma unroll
    for (int ks = 0; ks < 8; ks++)
        af2[ks] = *(const bf16x8*)&hs[(wrow0 + m) * 264 + ks * 32 + qo];

    const __bf16* pB2 = w2S + q * 1024 + m * 8;
    for (int nt = 0; nt < 8; nt++) {
        f32x4 o = {0.f, 0.f, 0.f, 0.f};
        #pragma unroll
        for (int ks = 0; ks < 8; ks++) {
            bf16x8 bfrag = *(const bf16x8*)(pB2 + nt * 128 + ks * 4096);
            o = __builtin_amdgcn_mfma_f32_16x16x32_bf16(af2[ks], bfrag, o, 0, 0, 0);
        }
        int n = nt * 16 + m;
        float s = g2[n] * rsqrtf(v2[n] + BN_EPS);
        float cc = (b2[n] - m2[n]) * s + bb2[n];
        #pragma unroll
        for (int r2 = 0; r2 < 4; r2++) {
            int orow = bm + rq + r2;
            if (orow < N_NODES) {
                float z = o[r2] * s + cc;
                xout[(size_t)orow * 128 + n] = (__bf16)fmaxf(z, 0.0f);
            }
        }
    }
}

// ---------------- pooling + head ----------------
// batch is sorted: accumulate runs in registers, atomic only at run boundaries.
__global__ void pool_kernel(const __bf16* __restrict__ xb, const int* __restrict__ batch,
                            float* __restrict__ pooled) {
    int c = threadIdx.x;               // 128 channels
    int n0 = blockIdx.x * 64;
    if (n0 >= N_NODES) return;
    int cur = batch[n0];
    float acc = 0.0f;
    int nend = (n0 + 64 < N_NODES) ? n0 + 64 : N_NODES;
    for (int node = n0; node < nend; node++) {
        int b = batch[node];
        if (b != cur) {
            unsafeAtomicAdd(&pooled[cur * 128 + c], acc);
            acc = 0.0f; cur = b;
        }
        acc += (float)xb[(size_t)node * 128 + c];
    }
    unsafeAtomicAdd(&pooled[cur * 128 + c], acc);
}

__global__ void final_kernel(const float* __restrict__ pooled,
                             const float* __restrict__ lw1, const float* __restrict__ lb1,
                             const float* __restrict__ g3, const float* __restrict__ b3,
                             const float* __restrict__ m3, const float* __restrict__ v3,
                             const float* __restrict__ lw2, const float* __restrict__ lb2,
                             float* __restrict__ out) {
    int gid = blockIdx.x;
    int t = threadIdx.x;
    __shared__ float p[128], hsf[128], lg[10];
    p[t] = pooled[gid * 128 + t];
    __syncthreads();
    float z = lb1[t];
    #pragma unroll 4
    for (int k = 0; k < 128; k++) z += p[k] * lw1[k * 128 + t];
    float h = (z - m3[t]) * rsqrtf(v3[t] + BN_EPS) * g3[t] + b3[t];
    hsf[t] = fmaxf(h, 0.0f);
    __syncthreads();
    if (t < 10) {
        float o = lb2[t];
        #pragma unroll 4
        for (int k = 0; k < 128; k++) o += hsf[k] * lw2[k * 10 + t];
        lg[t] = o;
    }
    __syncthreads();
    if (t < 10) {
        float mx = lg[0];
        for (int j = 1; j < 10; j++) mx = fmaxf(mx, lg[j]);
        float sum = 0.0f;
        for (int j = 0; j < 10; j++) sum += expf(lg[j] - mx);
        out[gid * 10 + t] = lg[t] - mx - logf(sum);
    }
}

// ---------------- launch ----------------

extern "C" void kernel_launch(void* const* d_in, const int* in_sizes, int n_in,
                              void* d_out, int out_size, void* d_ws, size_t ws_size,
                              hipStream_t stream) {
    (void)in_sizes; (void)n_in; (void)out_size; (void)ws_size;
    const float* x      = (const float*)d_in[0];
    const int*   ei     = (const int*)d_in[1];
    const int*   srcv   = ei;
    const int*   dstv   = ei + N_EDGES;
    const int*   batch  = (const int*)d_in[2];
    const float* w1     = (const float*)d_in[3];
    const float* b1     = (const float*)d_in[4];
    const float* bn1_g  = (const float*)d_in[5];
    const float* bn1_b  = (const float*)d_in[6];
    const float* bn1_m  = (const float*)d_in[7];
    const float* bn1_v  = (const float*)d_in[8];
    const float* geps   = (const float*)d_in[9];
    const float* w2     = (const float*)d_in[10];
    const float* b2     = (const float*)d_in[11];
    const float* bn2_g  = (const float*)d_in[12];
    const float* bn2_b  = (const float*)d_in[13];
    const float* bn2_m  = (const float*)d_in[14];
    const float* bn2_v  = (const float*)d_in[15];
    const float* lw1    = (const float*)d_in[16];
    const float* lb1    = (const float*)d_in[17];
    const float* g3     = (const float*)d_in[18];
    const float* b3     = (const float*)d_in[19];
    const float* m3     = (const float*)d_in[20];
    const float* v3     = (const float*)d_in[21];
    const float* lw2    = (const float*)d_in[22];
    const float* lb2    = (const float*)d_in[23];
    float* out = (float*)d_out;

    char* ws = (char*)d_ws;
    __bf16* xb    = (__bf16*)(ws + 0);                 // 25.6 MB  (ping)
    __bf16* xb2   = (__bf16*)(ws + 25600000);          // 25.6 MB  (pong)
    // --- aliases in the region past xb2 (dead once gin_layer 0 runs) ---
    unsigned int* pairs = (unsigned int*)(ws + 51200000);   // 6.4 MB
    int*    bh    = (int*)   (ws + 57600000);          // 256*98*4 = 100352
    int*    offs  = (int*)   (ws + 57700352);          // 100352
    int*    bbase = (int*)   (ws + 57800704);          // 99*4
    int*    bsz   = (int*)   (ws + 57801200);          // 98*4
    // --- persistent ---
    __bf16* w1S   = (__bf16*)(ws + 76800000);
    __bf16* w2S   = (__bf16*)(ws + 77062144);
    int*    deg   = (int*)   (ws + 77324288);
    int*    part  = (int*)   (ws + 77724288);
    int*    rowp  = (int*)   (ws + 78124288);
    int*    eidx  = (int*)   (ws + 78524304);
    int*    bsum  = (int*)   (ws + 84924304);
    float*  pooled= (float*) (ws + 84925888);

    (void)hipMemsetAsync(deg, 0, N_NODES * sizeof(int), stream);
    (void)hipMemsetAsync(pooled, 0, N_GRAPHS * 128 * sizeof(float), stream);

    conv_x_kernel<<<(N_NODES * 128 / 4 + 255) / 256, 256, 0, stream>>>(x, xb);
    conv_w_kernel<<<(4 * 128 * 256 + 255) / 256, 256, 0, stream>>>(w1, w2, w1S, w2S);

    // CSR build: degrees+bucket histograms, scans, deterministic binning, local fill
    count_kernel<<<NBLK, 256, 0, stream>>>(dstv, deg, bh);

    int nb = (N_NODES + 255) / 256;  // 391
    scan_blocks_kernel<<<nb, 256, 0, stream>>>(deg, part, bsum, N_NODES);
    scan_bsums_kernel<<<1, 512, 0, stream>>>(bsum, nb);
    add_offsets_kernel<<<nb, 256, 0, stream>>>(part, bsum, rowp, N_NODES);

    scan_col_kernel<<<NB, 256, 0, stream>>>(bh, offs, bsz);
    scan_base_kernel<<<1, 128, 0, stream>>>(bsz, bbase);
    bin_place_kernel<<<NBLK, 256, 0, stream>>>(srcv, dstv, offs, bbase, pairs);
    fill2_kernel<<<NB, 256, 0, stream>>>(pairs, bbase, rowp, eidx);

    int mblocks = (N_NODES + 63) / 64;  // 1563
    __bf16* xin = xb;
    __bf16* xout = xb2;
    for (int l = 0; l < 4; l++) {
        gin_layer<<<mblocks, 256, 0, stream>>>(
            xin, rowp, eidx, w1S + l * 32768, w2S + l * 32768,
            b1 + l * 256, bn1_g + l * 256, bn1_b + l * 256, bn1_m + l * 256, bn1_v + l * 256,
            b2 + l * 128, bn2_g + l * 128, bn2_b + l * 128, bn2_m + l * 128, bn2_v + l * 128,
            geps, l, xout);
        __bf16* t = xin; xin = xout; xout = t;
    }
    // after 4 layers, final x is in xin == xb

    pool_kernel<<<(N_NODES + 63) / 64, 128, 0, stream>>>(xin, batch, pooled);
    final_kernel<<<N_GRAPHS, 128, 0, stream>>>(pooled, lw1, lb1, g3, b3, m3, v3, lw2, lb2, out);
}